// Round 2
// baseline (1920.029 us; speedup 1.0000x reference)
//
#include <hip/hip_runtime.h>
#include <hip/hip_bf16.h>

#define B_ 128
#define T_ 20
#define D_ 512
#define H_ 512
#define V_ 32000
#define NCLS_ 1000
#define TOPK_ 5
#define G3_ 1536   // 3*H
#define NEG_HUGE (-3.402823466e38f)

typedef __bf16 bfx8 __attribute__((ext_vector_type(8)));
typedef float f32x4 __attribute__((ext_vector_type(4)));

static __device__ inline unsigned short f2bf(float x) {
    __hip_bfloat16 b = __float2bfloat16(x);
    return __builtin_bit_cast(unsigned short, b);
}

// ---------------------------------------------------------------- transpose
__global__ void transpose_kernel(const float* __restrict__ src, float* __restrict__ dst,
                                 int rows, int cols) {
    __shared__ float tile[32][33];
    int c0 = blockIdx.x * 32, r0 = blockIdx.y * 32;
    int x = threadIdx.x, y0 = threadIdx.y;              // block (32,8)
    for (int yy = y0; yy < 32; yy += 8) {
        int r = r0 + yy, c = c0 + x;
        if (r < rows && c < cols) tile[yy][x] = src[(size_t)r * cols + c];
    }
    __syncthreads();
    for (int yy = y0; yy < 32; yy += 8) {
        int r = r0 + x, c = c0 + yy;
        if (r < rows && c < cols) dst[(size_t)c * rows + r] = tile[x][yy];
    }
}

// ------------------------------------------------- top-k(5) + class-emb mean
__global__ void topk_cls_kernel(const float* __restrict__ img,
                                const float* __restrict__ class_emb,
                                float* __restrict__ cls) {
    int b = blockIdx.x;
    int tid = threadIdx.x;
    __shared__ float svals[256];
    __shared__ int   sidx[256];
    __shared__ int   chosen[TOPK_];
    const float* row = img + (size_t)b * NCLS_;
    for (int it = 0; it < TOPK_; ++it) {
        float best = NEG_HUGE; int bi = NCLS_;
        for (int i = tid; i < NCLS_; i += 256) {
            bool excl = false;
            for (int j = 0; j < it; ++j) excl = excl || (chosen[j] == i);
            float v = excl ? NEG_HUGE : row[i];
            if (v > best || (v == best && i < bi)) { best = v; bi = i; }
        }
        svals[tid] = best; sidx[tid] = bi;
        __syncthreads();
        for (int s = 128; s > 0; s >>= 1) {
            if (tid < s) {
                float v2 = svals[tid + s]; int i2 = sidx[tid + s];
                if (v2 > svals[tid] || (v2 == svals[tid] && i2 < sidx[tid])) {
                    svals[tid] = v2; sidx[tid] = i2;
                }
            }
            __syncthreads();
        }
        if (tid == 0) chosen[it] = sidx[0];
        __syncthreads();
    }
    for (int d = tid; d < D_; d += 256) {
        float s = 0.f;
        for (int j = 0; j < TOPK_; ++j) s += class_emb[(size_t)chosen[j] * D_ + d];
        cls[(size_t)b * D_ + d] = s * (1.0f / TOPK_);
    }
}

// ------------------------------------------------------- proj = cls @ W^T + b
__global__ void proj_kernel(const float* __restrict__ cls, const float* __restrict__ projWT,
                            const float* __restrict__ proj_b, float* __restrict__ proj) {
    int b = blockIdx.x, tid = threadIdx.x;
    __shared__ float x[D_];
    for (int k = tid; k < D_; k += 256) x[k] = cls[(size_t)b * D_ + k];
    __syncthreads();
    float a0 = 0.f, a1 = 0.f;
    for (int k = 0; k < D_; ++k) {
        float xv = x[k];
        a0 += xv * projWT[(size_t)k * D_ + tid];
        a1 += xv * projWT[(size_t)k * D_ + tid + 256];
    }
    proj[(size_t)b * D_ + tid]       = a0 + proj_b[tid];
    proj[(size_t)b * D_ + tid + 256] = a1 + proj_b[tid + 256];
}

// ------------------------------------------------- batchnorm (train, biased)
__global__ void bn_kernel(float* __restrict__ proj, const float* __restrict__ gamma,
                          const float* __restrict__ beta) {
    int j = blockIdx.x, b = threadIdx.x;   // 128 threads
    float v = proj[(size_t)b * D_ + j];
    __shared__ float ssum[128], ssq[128];
    ssum[b] = v; ssq[b] = v * v;
    __syncthreads();
    for (int s = 64; s > 0; s >>= 1) {
        if (b < s) { ssum[b] += ssum[b + s]; ssq[b] += ssq[b + s]; }
        __syncthreads();
    }
    float mu  = ssum[0] * (1.0f / B_);
    float var = ssq[0] * (1.0f / B_) - mu * mu;
    float inv = 1.0f / sqrtf(var + 1e-5f);
    proj[(size_t)b * D_ + j] = (v - mu) * inv * gamma[j] + beta[j];
}

// ------------------------------------- gi_all[b,t,:] = x[b,t,:] @ Wih^T + bih
__global__ void gi_all_kernel(const float* __restrict__ proj, const float* __restrict__ emb,
                              const int* __restrict__ targets, const float* __restrict__ WihT,
                              const float* __restrict__ bih, float* __restrict__ gi) {
    int r0 = blockIdx.x * 8, tid = threadIdx.x;
    __shared__ float xs[8][D_];
    for (int e = tid; e < 8 * D_; e += 256) {
        int lr = e >> 9, k = e & 511;
        int r = r0 + lr, b = r / T_, t = r % T_;
        const float* src = (t == 0) ? (proj + (size_t)b * D_)
                                    : (emb + (size_t)targets[b * T_ + t - 1] * D_);
        xs[lr][k] = src[k];
    }
    __syncthreads();
    float acc[8][6] = {};
    int c0 = tid;
    for (int k = 0; k < D_; ++k) {
        float w[6];
#pragma unroll
        for (int j = 0; j < 6; ++j) w[j] = WihT[(size_t)k * G3_ + c0 + j * 256];
#pragma unroll
        for (int lr = 0; lr < 8; ++lr) {
            float xv = xs[lr][k];
#pragma unroll
            for (int j = 0; j < 6; ++j) acc[lr][j] += xv * w[j];
        }
    }
    for (int lr = 0; lr < 8; ++lr) {
        size_t base = (size_t)(r0 + lr) * G3_;
#pragma unroll
        for (int j = 0; j < 6; ++j) gi[base + c0 + j * 256] = acc[lr][j] + bih[c0 + j * 256];
    }
}

// ------------------------------------------------- one GRU step (fused gates)
__global__ void gru_step_kernel(const float* __restrict__ gi_all, const float* __restrict__ WhhT,
                                const float* __restrict__ bhh, const int* __restrict__ real_lens,
                                float* __restrict__ h, float* __restrict__ outb, int t) {
    int b0 = blockIdx.x * 4, tid = threadIdx.x;
    __shared__ float hs[4][H_];
    for (int e = tid; e < 4 * H_; e += 256)
        hs[e >> 9][e & 511] = h[(size_t)(b0 + (e >> 9)) * H_ + (e & 511)];
    __syncthreads();
    float acc[4][6] = {};
    for (int k = 0; k < H_; ++k) {
        float w[6];
#pragma unroll
        for (int g = 0; g < 3; ++g)
#pragma unroll
            for (int nn = 0; nn < 2; ++nn)
                w[g * 2 + nn] = WhhT[(size_t)k * G3_ + g * 512 + nn * 256 + tid];
#pragma unroll
        for (int bb = 0; bb < 4; ++bb) {
            float hv = hs[bb][k];
#pragma unroll
            for (int j = 0; j < 6; ++j) acc[bb][j] += hv * w[j];
        }
    }
#pragma unroll
    for (int bb = 0; bb < 4; ++bb) {
        int b = b0 + bb;
        const float* gir = gi_all + (size_t)(b * T_ + t) * G3_;
        bool valid = t < real_lens[b];
#pragma unroll
        for (int nn = 0; nn < 2; ++nn) {
            int n = nn * 256 + tid;
            float ghr = acc[bb][0 + nn] + bhh[n];
            float ghz = acc[bb][2 + nn] + bhh[512 + n];
            float ghn = acc[bb][4 + nn] + bhh[1024 + n];
            float gr = gir[n], gz = gir[512 + n], gn = gir[1024 + n];
            float r  = 1.0f / (1.0f + expf(-(gr + ghr)));
            float z  = 1.0f / (1.0f + expf(-(gz + ghz)));
            float ng = tanhf(gn + r * ghn);
            float hold = hs[bb][n];
            float hnew = (1.0f - z) * ng + z * hold;
            h[(size_t)b * H_ + n] = hnew;
            outb[(size_t)(b * T_ + t) * H_ + n] = valid ? hnew : 0.0f;
        }
    }
}

// ------------------------------------------------- tmp = out @ attn_W
__global__ void attn_tmp_kernel(const float* __restrict__ outb, const float* __restrict__ attn_W,
                                float* __restrict__ tmp) {
    int r0 = blockIdx.x * 8, tid = threadIdx.x;
    __shared__ float xs[8][H_];
    for (int e = tid; e < 8 * H_; e += 256)
        xs[e >> 9][e & 511] = outb[(size_t)(r0 + (e >> 9)) * H_ + (e & 511)];
    __syncthreads();
    float a0[8] = {}, a1[8] = {};
    for (int d = 0; d < H_; ++d) {
        float w0 = attn_W[(size_t)d * H_ + tid];
        float w1 = attn_W[(size_t)d * H_ + tid + 256];
#pragma unroll
        for (int lr = 0; lr < 8; ++lr) {
            float xv = xs[lr][d];
            a0[lr] += xv * w0; a1[lr] += xv * w1;
        }
    }
    for (int lr = 0; lr < 8; ++lr) {
        tmp[(size_t)(r0 + lr) * H_ + tid]       = a0[lr];
        tmp[(size_t)(r0 + lr) * H_ + tid + 256] = a1[lr];
    }
}

// -------------------------- per (b,t): scores -> causal softmax -> ct
__global__ void attn_ct_kernel(const float* __restrict__ tmp, const float* __restrict__ outb,
                               float* __restrict__ ct) {
    int bt = blockIdx.x;
    int b = bt / T_, t = bt % T_;
    int tid = threadIdx.x;
    __shared__ float sc[32];
    __shared__ float al[32];
    const float* ob = outb + (size_t)b * T_ * H_;
    const float* tr = tmp + (size_t)bt * H_;
    int sg = tid >> 5, lane = tid & 31;
    for (int s = sg; s < t; s += 8) {
        float p = 0.f;
        const float* os = ob + (size_t)s * H_;
        for (int d = lane; d < H_; d += 32) p += tr[d] * os[d];
        for (int w = 16; w > 0; w >>= 1) p += __shfl_xor(p, w, 32);
        if (lane == 0) sc[s] = p;
    }
    __syncthreads();
    if (tid == 0 && t > 0) {
        float m = NEG_HUGE;
        for (int s = 0; s < t; ++s) m = fmaxf(m, sc[s]);
        float den = 0.f;
        for (int s = 0; s < t; ++s) { float e = expf(sc[s] - m); al[s] = e; den += e; }
        float inv = 1.0f / den;
        for (int s = 0; s < t; ++s) al[s] *= inv;
    }
    __syncthreads();
    float c0 = 0.f, c1 = 0.f;
    for (int s = 0; s < t; ++s) {
        float a = al[s];
        c0 += a * ob[(size_t)s * H_ + tid];
        c1 += a * ob[(size_t)s * H_ + tid + 256];
    }
    ct[(size_t)bt * H_ + tid]       = c0;
    ct[(size_t)bt * H_ + tid + 256] = c1;
}

// ------------------------------------------------- bf16 conversions
__global__ void feats_bf16_kernel(const float* __restrict__ outb, const float* __restrict__ ct,
                                  unsigned short* __restrict__ f) {
    size_t i = (size_t)blockIdx.x * 256 + threadIdx.x;   // over 2560*1024
    size_t r = i >> 10; int k = (int)(i & 1023);
    float v = (k < 512) ? outb[(r << 9) + k] : ct[(r << 9) + (k - 512)];
    f[i] = f2bf(v);
}

__global__ void w_bf16_kernel(const float4* __restrict__ w, ushort4* __restrict__ o) {
    size_t i = (size_t)blockIdx.x * 256 + threadIdx.x;   // 8192000 vec4s
    float4 v = w[i];
    ushort4 u;
    u.x = f2bf(v.x); u.y = f2bf(v.y); u.z = f2bf(v.z); u.w = f2bf(v.w);
    o[i] = u;
}

// ------------------------- logits = feats @ vocab_W^T + b  (bf16 MFMA GEMM)
// A: 2560x1024 bf16 row-major; Bw: 32000x1024 bf16 (B^T layout); C: f32
__global__ __launch_bounds__(256) void vocab_gemm_kernel(
    const unsigned short* __restrict__ A, const unsigned short* __restrict__ Bw,
    const float* __restrict__ bias, float* __restrict__ C) {
    // LDS layout: [kblk][row][8] -> fragment ds_read_b128 conflict-free
    __shared__ unsigned short As[4][128][8];
    __shared__ unsigned short Bs[4][128][8];
    const int K = 1024;
    int bid = blockIdx.x;
    int br = bid % 20, bc = bid / 20;          // M-fastest: 20 blocks share B panel
    int tid = threadIdx.x;
    int wave = tid >> 6, lane = tid & 63;
    int wr = wave >> 1, wc = wave & 1;
    int arow = tid >> 2, kblk = tid & 3;
    int lr = lane & 15, kb = lane >> 4;
    f32x4 acc[4][4] = {};
    const unsigned short* Ab = A + (size_t)(br * 128 + arow) * K + kblk * 8;
    const unsigned short* Bb = Bw + (size_t)(bc * 128 + arow) * K + kblk * 8;
    for (int kt = 0; kt < K / 32; ++kt) {
        bfx8 a0 = *(const bfx8*)(Ab + kt * 32);
        bfx8 a1 = *(const bfx8*)(Ab + (size_t)64 * K + kt * 32);
        bfx8 b0 = *(const bfx8*)(Bb + kt * 32);
        bfx8 b1 = *(const bfx8*)(Bb + (size_t)64 * K + kt * 32);
        __syncthreads();
        *(bfx8*)&As[kblk][arow][0]      = a0;
        *(bfx8*)&As[kblk][arow + 64][0] = a1;
        *(bfx8*)&Bs[kblk][arow][0]      = b0;
        *(bfx8*)&Bs[kblk][arow + 64][0] = b1;
        __syncthreads();
        bfx8 fa[4], fb[4];
#pragma unroll
        for (int m = 0; m < 4; ++m) fa[m] = *(const bfx8*)&As[kb][wr * 64 + m * 16 + lr][0];
#pragma unroll
        for (int n = 0; n < 4; ++n) fb[n] = *(const bfx8*)&Bs[kb][wc * 64 + n * 16 + lr][0];
#pragma unroll
        for (int m = 0; m < 4; ++m)
#pragma unroll
            for (int n = 0; n < 4; ++n)
                acc[m][n] = __builtin_amdgcn_mfma_f32_16x16x32_bf16(fa[m], fb[n], acc[m][n], 0, 0, 0);
    }
#pragma unroll
    for (int m = 0; m < 4; ++m) {
        int row = br * 128 + wr * 64 + m * 16 + ((lane >> 4) * 4);
#pragma unroll
        for (int n = 0; n < 4; ++n) {
            int col = bc * 128 + wc * 64 + n * 16 + (lane & 15);
            float bv = bias[col];
#pragma unroll
            for (int r = 0; r < 4; ++r)
                C[(size_t)(row + r) * V_ + col] = acc[m][n][r] + bv;
        }
    }
}

// ---------------------------------------------------------------------------
extern "C" void kernel_launch(void* const* d_in, const int* in_sizes, int n_in,
                              void* d_out, int out_size, void* d_ws, size_t ws_size,
                              hipStream_t stream) {
    const float* img_rep   = (const float*)d_in[0];
    const int*   targets   = (const int*)d_in[1];
    const int*   real_lens = (const int*)d_in[2];
    const float* class_emb = (const float*)d_in[3];
    const float* proj_W    = (const float*)d_in[4];
    const float* proj_b    = (const float*)d_in[5];
    const float* bn_gamma  = (const float*)d_in[6];
    const float* bn_beta   = (const float*)d_in[7];
    const float* emb_table = (const float*)d_in[8];
    const float* gru_Wih   = (const float*)d_in[9];
    const float* gru_Whh   = (const float*)d_in[10];
    const float* gru_bih   = (const float*)d_in[11];
    const float* gru_bhh   = (const float*)d_in[12];
    const float* attn_W    = (const float*)d_in[13];
    const float* vocab_W   = (const float*)d_in[14];
    const float* vocab_b   = (const float*)d_in[15];
    float* out = (float*)d_out;

    char* ws = (char*)d_ws;
    size_t off = 0;
    auto alloc = [&](size_t bytes) { char* p = ws + off; off += (bytes + 255) & ~(size_t)255; return p; };
    float* cls    = (float*)alloc((size_t)B_ * D_ * 4);
    float* proj   = (float*)alloc((size_t)B_ * D_ * 4);
    float* projWT = (float*)alloc((size_t)D_ * D_ * 4);
    float* WihT   = (float*)alloc((size_t)D_ * G3_ * 4);
    float* WhhT   = (float*)alloc((size_t)H_ * G3_ * 4);
    float* gi     = (float*)alloc((size_t)B_ * T_ * G3_ * 4);
    float* h      = (float*)alloc((size_t)B_ * H_ * 4);
    float* outb   = (float*)alloc((size_t)B_ * T_ * H_ * 4);
    float* tmp    = (float*)alloc((size_t)B_ * T_ * H_ * 4);
    float* ct     = (float*)alloc((size_t)B_ * T_ * H_ * 4);
    unsigned short* featsB  = (unsigned short*)alloc((size_t)B_ * T_ * 2 * H_ * 2);
    unsigned short* vocabWb = (unsigned short*)alloc((size_t)V_ * 2 * H_ * 2);

    transpose_kernel<<<dim3(D_ / 32, D_ / 32), dim3(32, 8), 0, stream>>>(proj_W, projWT, D_, D_);
    transpose_kernel<<<dim3(D_ / 32, G3_ / 32), dim3(32, 8), 0, stream>>>(gru_Wih, WihT, G3_, D_);
    transpose_kernel<<<dim3(H_ / 32, G3_ / 32), dim3(32, 8), 0, stream>>>(gru_Whh, WhhT, G3_, H_);
    topk_cls_kernel<<<B_, 256, 0, stream>>>(img_rep, class_emb, cls);
    proj_kernel<<<B_, 256, 0, stream>>>(cls, projWT, proj_b, proj);
    bn_kernel<<<D_, 128, 0, stream>>>(proj, bn_gamma, bn_beta);
    gi_all_kernel<<<(B_ * T_) / 8, 256, 0, stream>>>(proj, emb_table, targets, WihT, gru_bih, gi);
    hipMemsetAsync(h, 0, (size_t)B_ * H_ * 4, stream);
    for (int t = 0; t < T_; ++t)
        gru_step_kernel<<<B_ / 4, 256, 0, stream>>>(gi, WhhT, gru_bhh, real_lens, h, outb, t);
    attn_tmp_kernel<<<(B_ * T_) / 8, 256, 0, stream>>>(outb, attn_W, tmp);
    attn_ct_kernel<<<B_ * T_, 256, 0, stream>>>(tmp, outb, ct);
    feats_bf16_kernel<<<(B_ * T_ * 2 * H_) / 256, 256, 0, stream>>>(outb, ct, featsB);
    w_bf16_kernel<<<((size_t)V_ * 2 * H_ / 4) / 256, 256, 0, stream>>>((const float4*)vocab_W, (ushort4*)vocabWb);
    vocab_gemm_kernel<<<(B_ * T_ / 128) * (V_ / 128), 256, 0, stream>>>(featsB, vocabWb, vocab_b, out);
}